// Round 2
// baseline (643.786 us; speedup 1.0000x reference)
//
#include <hip/hip_runtime.h>
#include <stdint.h>

#define N_NODES 262144
#define N_EDGES 16777216

// Monotone float<->uint encoding: preserves ordering, so uint atomicMax == float max.
__device__ __forceinline__ unsigned int enc_f32(float f) {
    unsigned int u = __float_as_uint(f);
    return (u & 0x80000000u) ? ~u : (u | 0x80000000u);
}
__device__ __forceinline__ float dec_f32(unsigned int e) {
    unsigned int u = (e & 0x80000000u) ? (e ^ 0x80000000u) : ~e;
    return __uint_as_float(u);
}

// Kernel 1a: agg_enc[i] = enc(xp[i]) (self-loop init) and xp_enc[i] = same (gather table).
__global__ void gnn_init2(const float* __restrict__ x,
                          unsigned int* __restrict__ agg_enc,
                          unsigned int* __restrict__ xp_enc) {
    int i = blockIdx.x * blockDim.x + threadIdx.x;
    if (i < N_NODES) {
        float2 v = reinterpret_cast<const float2*>(x)[i];
        unsigned int e = enc_f32(v.x * v.y);
        agg_enc[i] = e;
        xp_enc[i] = e;
    }
}

// Kernel 1b: init without workspace (agg only).
__global__ void gnn_init1(const float* __restrict__ x,
                          unsigned int* __restrict__ agg_enc) {
    int i = blockIdx.x * blockDim.x + threadIdx.x;
    if (i < N_NODES) {
        float2 v = reinterpret_cast<const float2*>(x)[i];
        agg_enc[i] = enc_f32(v.x * v.y);
    }
}

// Kernel 2a: edges via precomputed enc table (4B gather + 4B atomic, both L2-resident).
__global__ void gnn_edges_ws(const int* __restrict__ ei,
                             const unsigned int* __restrict__ xp_enc,
                             unsigned int* agg_enc) {
    const int4* src4 = reinterpret_cast<const int4*>(ei);
    const int4* dst4 = reinterpret_cast<const int4*>(ei + N_EDGES);
    int tid = blockIdx.x * blockDim.x + threadIdx.x;
    int stride = gridDim.x * blockDim.x;
    const int n4 = N_EDGES / 4;
    for (int e4 = tid; e4 < n4; e4 += stride) {
        int4 s = src4[e4];
        int4 d = dst4[e4];
        unsigned int va = xp_enc[s.x];
        unsigned int vb = xp_enc[s.y];
        unsigned int vc = xp_enc[s.z];
        unsigned int vd = xp_enc[s.w];
        atomicMax(&agg_enc[d.x], va);
        atomicMax(&agg_enc[d.y], vb);
        atomicMax(&agg_enc[d.z], vc);
        atomicMax(&agg_enc[d.w], vd);
    }
}

// Kernel 2b: edges gathering x directly (no workspace fallback).
__global__ void gnn_edges_direct(const float* __restrict__ x,
                                 const int* __restrict__ ei,
                                 unsigned int* agg_enc) {
    const int4* src4 = reinterpret_cast<const int4*>(ei);
    const int4* dst4 = reinterpret_cast<const int4*>(ei + N_EDGES);
    const float2* x2 = reinterpret_cast<const float2*>(x);
    int tid = blockIdx.x * blockDim.x + threadIdx.x;
    int stride = gridDim.x * blockDim.x;
    const int n4 = N_EDGES / 4;
    for (int e4 = tid; e4 < n4; e4 += stride) {
        int4 s = src4[e4];
        int4 d = dst4[e4];
        float2 a = x2[s.x], b = x2[s.y], c = x2[s.z], e = x2[s.w];
        atomicMax(&agg_enc[d.x], enc_f32(a.x * a.y));
        atomicMax(&agg_enc[d.y], enc_f32(b.x * b.y));
        atomicMax(&agg_enc[d.z], enc_f32(c.x * c.y));
        atomicMax(&agg_enc[d.w], enc_f32(e.x * e.y));
    }
}

// Kernel 3: out[i] = xp[i]*w0 + dec(agg_enc[i])*w1   (in-place over the uint buffer)
__global__ void gnn_final(const float* __restrict__ x,
                          const float* __restrict__ w,
                          float* out) {
    int i = blockIdx.x * blockDim.x + threadIdx.x;
    if (i < N_NODES) {
        float2 v = reinterpret_cast<const float2*>(x)[i];
        float xp = v.x * v.y;
        unsigned int e = reinterpret_cast<const unsigned int*>(out)[i];
        float agg = dec_f32(e);
        out[i] = xp * w[0] + agg * w[1];
    }
}

extern "C" void kernel_launch(void* const* d_in, const int* in_sizes, int n_in,
                              void* d_out, int out_size, void* d_ws, size_t ws_size,
                              hipStream_t stream) {
    const float* x = (const float*)d_in[0];
    const int* ei = (const int*)d_in[1];     // int32 per harness contract (2 x N_EDGES)
    const float* w = (const float*)d_in[2];
    float* out = (float*)d_out;
    unsigned int* agg_enc = (unsigned int*)d_out;

    const int BLK = 256;
    const int nblk_nodes = (N_NODES + BLK - 1) / BLK;   // 1024
    const int nblk_edges = 2048;                        // grid-stride over 4M int4 groups

    if (ws_size >= (size_t)N_NODES * sizeof(unsigned int)) {
        unsigned int* xp_enc = (unsigned int*)d_ws;
        gnn_init2<<<nblk_nodes, BLK, 0, stream>>>(x, agg_enc, xp_enc);
        gnn_edges_ws<<<nblk_edges, BLK, 0, stream>>>(ei, xp_enc, agg_enc);
    } else {
        gnn_init1<<<nblk_nodes, BLK, 0, stream>>>(x, agg_enc);
        gnn_edges_direct<<<nblk_edges, BLK, 0, stream>>>(x, ei, agg_enc);
    }
    gnn_final<<<nblk_nodes, BLK, 0, stream>>>(x, w, out);
}

// Round 3
// 378.131 us; speedup vs baseline: 1.7025x; 1.7025x over previous
//
#include <hip/hip_runtime.h>
#include <stdint.h>

#define N_NODES 262144
#define N_EDGES 16777216

// Monotone float<->uint encoding: preserves ordering, so uint atomicMax == float max.
__device__ __forceinline__ unsigned int enc_f32(float f) {
    unsigned int u = __float_as_uint(f);
    return (u & 0x80000000u) ? ~u : (u | 0x80000000u);
}
__device__ __forceinline__ float dec_f32(unsigned int e) {
    unsigned int u = (e & 0x80000000u) ? (e ^ 0x80000000u) : ~e;
    return __uint_as_float(u);
}

// Kernel 1a: agg_enc[i] = enc(xp[i]) (self-loop init) and xp_enc[i] = same (gather table).
__global__ void gnn_init2(const float* __restrict__ x,
                          unsigned int* __restrict__ agg_enc,
                          unsigned int* __restrict__ xp_enc) {
    int i = blockIdx.x * blockDim.x + threadIdx.x;
    if (i < N_NODES) {
        float2 v = reinterpret_cast<const float2*>(x)[i];
        unsigned int e = enc_f32(v.x * v.y);
        agg_enc[i] = e;
        xp_enc[i] = e;
    }
}

// Kernel 1b: init without workspace (agg only).
__global__ void gnn_init1(const float* __restrict__ x,
                          unsigned int* __restrict__ agg_enc) {
    int i = blockIdx.x * blockDim.x + threadIdx.x;
    if (i < N_NODES) {
        float2 v = reinterpret_cast<const float2*>(x)[i];
        agg_enc[i] = enc_f32(v.x * v.y);
    }
}

// Kernel 2a: edges via precomputed enc table. Read-filter before atomic:
// agg_enc values only grow, so a (possibly stale) read is always <= final.
// If candidate <= read value, some write >= candidate already happened -> safe skip.
__global__ void gnn_edges_ws(const int* __restrict__ ei,
                             const unsigned int* __restrict__ xp_enc,
                             unsigned int* agg_enc) {
    const int4* src4 = reinterpret_cast<const int4*>(ei);
    const int4* dst4 = reinterpret_cast<const int4*>(ei + N_EDGES);
    int tid = blockIdx.x * blockDim.x + threadIdx.x;
    int stride = gridDim.x * blockDim.x;
    const int n4 = N_EDGES / 4;
    for (int e4 = tid; e4 < n4; e4 += stride) {
        int4 s = src4[e4];
        int4 d = dst4[e4];
        unsigned int va = xp_enc[s.x];
        unsigned int vb = xp_enc[s.y];
        unsigned int vc = xp_enc[s.z];
        unsigned int vd = xp_enc[s.w];
        unsigned int ca = agg_enc[d.x];
        unsigned int cb = agg_enc[d.y];
        unsigned int cc = agg_enc[d.z];
        unsigned int cd = agg_enc[d.w];
        if (va > ca) atomicMax(&agg_enc[d.x], va);
        if (vb > cb) atomicMax(&agg_enc[d.y], vb);
        if (vc > cc) atomicMax(&agg_enc[d.z], vc);
        if (vd > cd) atomicMax(&agg_enc[d.w], vd);
    }
}

// Kernel 2b: edges gathering x directly (no workspace fallback), same filter.
__global__ void gnn_edges_direct(const float* __restrict__ x,
                                 const int* __restrict__ ei,
                                 unsigned int* agg_enc) {
    const int4* src4 = reinterpret_cast<const int4*>(ei);
    const int4* dst4 = reinterpret_cast<const int4*>(ei + N_EDGES);
    const float2* x2 = reinterpret_cast<const float2*>(x);
    int tid = blockIdx.x * blockDim.x + threadIdx.x;
    int stride = gridDim.x * blockDim.x;
    const int n4 = N_EDGES / 4;
    for (int e4 = tid; e4 < n4; e4 += stride) {
        int4 s = src4[e4];
        int4 d = dst4[e4];
        float2 a = x2[s.x], b = x2[s.y], c = x2[s.z], e = x2[s.w];
        unsigned int va = enc_f32(a.x * a.y);
        unsigned int vb = enc_f32(b.x * b.y);
        unsigned int vc = enc_f32(c.x * c.y);
        unsigned int vd = enc_f32(e.x * e.y);
        unsigned int ca = agg_enc[d.x];
        unsigned int cb = agg_enc[d.y];
        unsigned int cc = agg_enc[d.z];
        unsigned int cd = agg_enc[d.w];
        if (va > ca) atomicMax(&agg_enc[d.x], va);
        if (vb > cb) atomicMax(&agg_enc[d.y], vb);
        if (vc > cc) atomicMax(&agg_enc[d.z], vc);
        if (vd > cd) atomicMax(&agg_enc[d.w], vd);
    }
}

// Kernel 3: out[i] = xp[i]*w0 + dec(agg_enc[i])*w1   (in-place over the uint buffer)
__global__ void gnn_final(const float* __restrict__ x,
                          const float* __restrict__ w,
                          float* out) {
    int i = blockIdx.x * blockDim.x + threadIdx.x;
    if (i < N_NODES) {
        float2 v = reinterpret_cast<const float2*>(x)[i];
        float xp = v.x * v.y;
        unsigned int e = reinterpret_cast<const unsigned int*>(out)[i];
        float agg = dec_f32(e);
        out[i] = xp * w[0] + agg * w[1];
    }
}

extern "C" void kernel_launch(void* const* d_in, const int* in_sizes, int n_in,
                              void* d_out, int out_size, void* d_ws, size_t ws_size,
                              hipStream_t stream) {
    const float* x = (const float*)d_in[0];
    const int* ei = (const int*)d_in[1];     // int32 per harness contract (2 x N_EDGES)
    const float* w = (const float*)d_in[2];
    float* out = (float*)d_out;
    unsigned int* agg_enc = (unsigned int*)d_out;

    const int BLK = 256;
    const int nblk_nodes = (N_NODES + BLK - 1) / BLK;   // 1024
    const int nblk_edges = 2048;                        // grid-stride over 4M int4 groups

    if (ws_size >= (size_t)N_NODES * sizeof(unsigned int)) {
        unsigned int* xp_enc = (unsigned int*)d_ws;
        gnn_init2<<<nblk_nodes, BLK, 0, stream>>>(x, agg_enc, xp_enc);
        gnn_edges_ws<<<nblk_edges, BLK, 0, stream>>>(ei, xp_enc, agg_enc);
    } else {
        gnn_init1<<<nblk_nodes, BLK, 0, stream>>>(x, agg_enc);
        gnn_edges_direct<<<nblk_edges, BLK, 0, stream>>>(x, ei, agg_enc);
    }
    gnn_final<<<nblk_nodes, BLK, 0, stream>>>(x, w, out);
}

// Round 4
// 333.600 us; speedup vs baseline: 1.9298x; 1.1335x over previous
//
#include <hip/hip_runtime.h>
#include <stdint.h>

#define N_NODES 262144
#define N_EDGES 16777216

typedef int vint4 __attribute__((ext_vector_type(4)));

// Monotone float<->uint encoding: preserves ordering, so uint atomicMax == float max.
__device__ __forceinline__ unsigned int enc_f32(float f) {
    unsigned int u = __float_as_uint(f);
    return (u & 0x80000000u) ? ~u : (u | 0x80000000u);
}
__device__ __forceinline__ float dec_f32(unsigned int e) {
    unsigned int u = (e & 0x80000000u) ? (e ^ 0x80000000u) : ~e;
    return __uint_as_float(u);
}

// Kernel 1a: agg_enc[i] = enc(xp[i]) (self-loop init) and xp_enc[i] = same (gather table).
__global__ void gnn_init2(const float* __restrict__ x,
                          unsigned int* __restrict__ agg_enc,
                          unsigned int* __restrict__ xp_enc) {
    int i = blockIdx.x * blockDim.x + threadIdx.x;
    if (i < N_NODES) {
        float2 v = reinterpret_cast<const float2*>(x)[i];
        unsigned int e = enc_f32(v.x * v.y);
        agg_enc[i] = e;
        xp_enc[i] = e;
    }
}

// Kernel 1b: init without workspace (agg only).
__global__ void gnn_init1(const float* __restrict__ x,
                          unsigned int* __restrict__ agg_enc) {
    int i = blockIdx.x * blockDim.x + threadIdx.x;
    if (i < N_NODES) {
        float2 v = reinterpret_cast<const float2*>(x)[i];
        agg_enc[i] = enc_f32(v.x * v.y);
    }
}

// Kernel 2a: 16 edges per thread, single macro-iteration. Batch phases:
// (1) 8 non-temporal int4 index loads, (2) 16 gathers, (3) 16 filter reads,
// (4) filtered atomics. Maximizes outstanding scattered reads per wave.
__global__ __launch_bounds__(256) void gnn_edges_ws(const int* __restrict__ ei,
                                                    const unsigned int* __restrict__ xp_enc,
                                                    unsigned int* agg_enc) {
    const vint4* src4 = reinterpret_cast<const vint4*>(ei);
    const vint4* dst4 = reinterpret_cast<const vint4*>(ei + N_EDGES);
    const int T = gridDim.x * blockDim.x;           // 1,048,576 threads
    const int t = blockIdx.x * blockDim.x + threadIdx.x;

    vint4 s[4], d[4];
#pragma unroll
    for (int k = 0; k < 4; ++k) s[k] = __builtin_nontemporal_load(&src4[t + k * T]);
#pragma unroll
    for (int k = 0; k < 4; ++k) d[k] = __builtin_nontemporal_load(&dst4[t + k * T]);

    unsigned int v[16];
#pragma unroll
    for (int k = 0; k < 4; ++k)
#pragma unroll
        for (int j = 0; j < 4; ++j) v[k * 4 + j] = xp_enc[s[k][j]];

    unsigned int c[16];
#pragma unroll
    for (int k = 0; k < 4; ++k)
#pragma unroll
        for (int j = 0; j < 4; ++j) c[k * 4 + j] = agg_enc[d[k][j]];

#pragma unroll
    for (int k = 0; k < 4; ++k)
#pragma unroll
        for (int j = 0; j < 4; ++j) {
            int i = k * 4 + j;
            if (v[i] > c[i]) atomicMax(&agg_enc[d[k][j]], v[i]);
        }
}

// Kernel 2b fallback (no workspace): grid-stride, direct x gather, same filter.
__global__ void gnn_edges_direct(const float* __restrict__ x,
                                 const int* __restrict__ ei,
                                 unsigned int* agg_enc) {
    const int4* src4 = reinterpret_cast<const int4*>(ei);
    const int4* dst4 = reinterpret_cast<const int4*>(ei + N_EDGES);
    const float2* x2 = reinterpret_cast<const float2*>(x);
    int tid = blockIdx.x * blockDim.x + threadIdx.x;
    int stride = gridDim.x * blockDim.x;
    const int n4 = N_EDGES / 4;
    for (int e4 = tid; e4 < n4; e4 += stride) {
        int4 s = src4[e4];
        int4 d = dst4[e4];
        float2 a = x2[s.x], b = x2[s.y], c = x2[s.z], e = x2[s.w];
        unsigned int va = enc_f32(a.x * a.y);
        unsigned int vb = enc_f32(b.x * b.y);
        unsigned int vc = enc_f32(c.x * c.y);
        unsigned int vd = enc_f32(e.x * e.y);
        unsigned int ca = agg_enc[d.x];
        unsigned int cb = agg_enc[d.y];
        unsigned int cc = agg_enc[d.z];
        unsigned int cd = agg_enc[d.w];
        if (va > ca) atomicMax(&agg_enc[d.x], va);
        if (vb > cb) atomicMax(&agg_enc[d.y], vb);
        if (vc > cc) atomicMax(&agg_enc[d.z], vc);
        if (vd > cd) atomicMax(&agg_enc[d.w], vd);
    }
}

// Kernel 3: out[i] = xp[i]*w0 + dec(agg_enc[i])*w1   (in-place over the uint buffer)
__global__ void gnn_final(const float* __restrict__ x,
                          const float* __restrict__ w,
                          float* out) {
    int i = blockIdx.x * blockDim.x + threadIdx.x;
    if (i < N_NODES) {
        float2 v = reinterpret_cast<const float2*>(x)[i];
        float xp = v.x * v.y;
        unsigned int e = reinterpret_cast<const unsigned int*>(out)[i];
        float agg = dec_f32(e);
        out[i] = xp * w[0] + agg * w[1];
    }
}

extern "C" void kernel_launch(void* const* d_in, const int* in_sizes, int n_in,
                              void* d_out, int out_size, void* d_ws, size_t ws_size,
                              hipStream_t stream) {
    const float* x = (const float*)d_in[0];
    const int* ei = (const int*)d_in[1];     // int32 per harness contract (2 x N_EDGES)
    const float* w = (const float*)d_in[2];
    float* out = (float*)d_out;
    unsigned int* agg_enc = (unsigned int*)d_out;

    const int BLK = 256;
    const int nblk_nodes = (N_NODES + BLK - 1) / BLK;   // 1024

    if (ws_size >= (size_t)N_NODES * sizeof(unsigned int)) {
        unsigned int* xp_enc = (unsigned int*)d_ws;
        gnn_init2<<<nblk_nodes, BLK, 0, stream>>>(x, agg_enc, xp_enc);
        // 4096 blocks x 256 threads x 16 edges = 16,777,216 edges exactly
        gnn_edges_ws<<<4096, BLK, 0, stream>>>(ei, xp_enc, agg_enc);
    } else {
        gnn_init1<<<nblk_nodes, BLK, 0, stream>>>(x, agg_enc);
        gnn_edges_direct<<<2048, BLK, 0, stream>>>(x, ei, agg_enc);
    }
    gnn_final<<<nblk_nodes, BLK, 0, stream>>>(x, w, out);
}

// Round 5
// 153.094 us; speedup vs baseline: 4.2052x; 2.1791x over previous
//
#include <hip/hip_runtime.h>
#include <stdint.h>

#define N_NODES 262144
#define N_EDGES 16777216

#define NBINS   256
#define SLICE   1024                 // N_NODES / NBINS
#define CHUNK   4096                 // edges per phase-1 block
#define NCHUNK  (N_EDGES / CHUNK)    // 4096 blocks
#define BINCAP  69632                // 65536 avg + 4096 slack (+12 sigma)

#define WS_CURSOR_OFF 0u             // 256 * 4B cursors
#define WS_XP_OFF     4096u          // 1 MB xp_enc table (read-only during phase 1)
#define WS_BINS_OFF   (4096u + (unsigned)N_NODES * 4u)  // pair bins
#define WS_NEEDED     ((size_t)WS_BINS_OFF + (size_t)NBINS * BINCAP * 8u)

typedef int vint4 __attribute__((ext_vector_type(4)));

// Monotone float<->uint encoding: preserves ordering, so uint atomicMax == float max.
__device__ __forceinline__ unsigned int enc_f32(float f) {
    unsigned int u = __float_as_uint(f);
    return (u & 0x80000000u) ? ~u : (u | 0x80000000u);
}
__device__ __forceinline__ float dec_f32(unsigned int e) {
    unsigned int u = (e & 0x80000000u) ? (e ^ 0x80000000u) : ~e;
    return __uint_as_float(u);
}

// ---------- partitioned path ----------

// Init: agg_enc[i] = xp_ws[i] = enc(xp[i]); zero bin cursors.
__global__ void k_init(const float* __restrict__ x,
                       unsigned int* __restrict__ agg_out,
                       unsigned int* __restrict__ xp_ws,
                       unsigned int* __restrict__ cursors) {
    int i = blockIdx.x * blockDim.x + threadIdx.x;
    if (i < NBINS) cursors[i] = 0;
    if (i < N_NODES) {
        float2 v = reinterpret_cast<const float2*>(x)[i];
        unsigned int e = enc_f32(v.x * v.y);
        agg_out[i] = e;
        xp_ws[i] = e;
    }
}

// Phase 1: stream edges, gather src value, partition (dst,val) pairs into
// 256 dst-bins via LDS staging + global cursor reservation.
__global__ __launch_bounds__(256) void k_part(const int* __restrict__ ei,
                                              const unsigned int* __restrict__ xp,
                                              unsigned long long* __restrict__ bins,
                                              unsigned int* __restrict__ cursors,
                                              unsigned int* __restrict__ agg_out) {
    __shared__ unsigned long long stag[CHUNK];          // 32 KB
    __shared__ unsigned int cnt[NBINS];
    __shared__ unsigned int incl[NBINS];
    __shared__ unsigned int exs[NBINS];
    __shared__ unsigned int pos[NBINS];
    __shared__ unsigned int gbase[NBINS];

    const int t = threadIdx.x;
    const int g = blockIdx.x;
    const vint4* src4 = reinterpret_cast<const vint4*>(ei);
    const vint4* dst4 = reinterpret_cast<const vint4*>(ei + N_EDGES);

    // 16 edges per thread, coalesced int4 loads, non-temporal (stream).
    vint4 s[4], d[4];
#pragma unroll
    for (int k = 0; k < 4; ++k) s[k] = __builtin_nontemporal_load(&src4[g * 1024 + k * 256 + t]);
#pragma unroll
    for (int k = 0; k < 4; ++k) d[k] = __builtin_nontemporal_load(&dst4[g * 1024 + k * 256 + t]);

    // Gather source values from the read-only ws table (never atomic-dirtied).
    unsigned int val[16];
#pragma unroll
    for (int k = 0; k < 4; ++k)
#pragma unroll
        for (int j = 0; j < 4; ++j) val[k * 4 + j] = xp[s[k][j]];

    unsigned int bn[16];
#pragma unroll
    for (int k = 0; k < 4; ++k)
#pragma unroll
        for (int j = 0; j < 4; ++j) bn[k * 4 + j] = ((unsigned int)d[k][j]) >> 10;

    cnt[t] = 0;
    __syncthreads();
#pragma unroll
    for (int i = 0; i < 16; ++i) atomicAdd(&cnt[bn[i]], 1u);
    __syncthreads();

    // Hillis-Steele inclusive scan over 256 bins (blockDim == NBINS == 256).
    incl[t] = cnt[t];
    __syncthreads();
    for (int st = 1; st < NBINS; st <<= 1) {
        unsigned int u = (t >= st) ? incl[t - st] : 0u;
        __syncthreads();
        incl[t] += u;
        __syncthreads();
    }
    exs[t] = incl[t] - cnt[t];
    pos[t] = exs[t];
    // Reserve global space for this chunk's bin segments.
    gbase[t] = atomicAdd(&cursors[t], cnt[t]);
    __syncthreads();

    // Scatter pairs into LDS staging, ordered by bin.
#pragma unroll
    for (int k = 0; k < 4; ++k)
#pragma unroll
        for (int j = 0; j < 4; ++j) {
            int i = k * 4 + j;
            unsigned int slot = atomicAdd(&pos[bn[i]], 1u);
            stag[slot] = ((unsigned long long)(unsigned int)d[k][j] << 32) | val[i];
        }
    __syncthreads();

    // Flush staged segments to global bins (coalesced within segments).
    for (int i = t; i < CHUNK; i += 256) {
        unsigned long long p = stag[i];
        unsigned int dst = (unsigned int)(p >> 32);
        unsigned int bb = dst >> 10;
        unsigned int gp = gbase[bb] + (unsigned int)i - exs[bb];
        if (gp < BINCAP) {
            bins[(size_t)bb * BINCAP + gp] = p;
        } else {
            // Overflow fallback (statistically unreachable): filtered global atomic.
            unsigned int v = (unsigned int)p;
            unsigned int c = agg_out[dst];
            if (v > c) atomicMax(&agg_out[dst], v);
        }
    }
}

// Phase 2: one block per bin. LDS-private max table, fused epilogue.
__global__ __launch_bounds__(1024) void k_reduce(const float* __restrict__ x,
                                                 const float* __restrict__ w,
                                                 const unsigned long long* __restrict__ bins,
                                                 const unsigned int* __restrict__ cursors,
                                                 float* __restrict__ out) {
    __shared__ unsigned int table[SLICE];
    const int b = blockIdx.x;
    const int t = threadIdx.x;

    unsigned int n = cursors[b];
    if (n > BINCAP) n = BINCAP;

    // Init from current agg (enc(xp) self-loop + any overflow atomics).
    const unsigned int* aggu = reinterpret_cast<const unsigned int*>(out);
    table[t] = aggu[b * SLICE + t];
    __syncthreads();

    const unsigned long long* mybin = bins + (size_t)b * BINCAP;
    for (unsigned int i = t; i < n; i += 1024) {
        unsigned long long p = __builtin_nontemporal_load(&mybin[i]);
        atomicMax(&table[(unsigned int)(p >> 32) & (SLICE - 1)], (unsigned int)p);
    }
    __syncthreads();

    int idx = b * SLICE + t;
    float2 v = reinterpret_cast<const float2*>(x)[idx];
    float xp = v.x * v.y;
    float agg = dec_f32(table[t]);
    out[idx] = xp * w[0] + agg * w[1];
}

// ---------- fallback path (R4) ----------

__global__ void gnn_init2(const float* __restrict__ x,
                          unsigned int* __restrict__ agg_enc,
                          unsigned int* __restrict__ xp_enc) {
    int i = blockIdx.x * blockDim.x + threadIdx.x;
    if (i < N_NODES) {
        float2 v = reinterpret_cast<const float2*>(x)[i];
        unsigned int e = enc_f32(v.x * v.y);
        agg_enc[i] = e;
        xp_enc[i] = e;
    }
}

__global__ void gnn_init1(const float* __restrict__ x,
                          unsigned int* __restrict__ agg_enc) {
    int i = blockIdx.x * blockDim.x + threadIdx.x;
    if (i < N_NODES) {
        float2 v = reinterpret_cast<const float2*>(x)[i];
        agg_enc[i] = enc_f32(v.x * v.y);
    }
}

__global__ __launch_bounds__(256) void gnn_edges_ws(const int* __restrict__ ei,
                                                    const unsigned int* __restrict__ xp_enc,
                                                    unsigned int* agg_enc) {
    const vint4* src4 = reinterpret_cast<const vint4*>(ei);
    const vint4* dst4 = reinterpret_cast<const vint4*>(ei + N_EDGES);
    const int T = gridDim.x * blockDim.x;
    const int t = blockIdx.x * blockDim.x + threadIdx.x;

    vint4 s[4], d[4];
#pragma unroll
    for (int k = 0; k < 4; ++k) s[k] = __builtin_nontemporal_load(&src4[t + k * T]);
#pragma unroll
    for (int k = 0; k < 4; ++k) d[k] = __builtin_nontemporal_load(&dst4[t + k * T]);

    unsigned int v[16];
#pragma unroll
    for (int k = 0; k < 4; ++k)
#pragma unroll
        for (int j = 0; j < 4; ++j) v[k * 4 + j] = xp_enc[s[k][j]];

    unsigned int c[16];
#pragma unroll
    for (int k = 0; k < 4; ++k)
#pragma unroll
        for (int j = 0; j < 4; ++j) c[k * 4 + j] = agg_enc[d[k][j]];

#pragma unroll
    for (int k = 0; k < 4; ++k)
#pragma unroll
        for (int j = 0; j < 4; ++j) {
            int i = k * 4 + j;
            if (v[i] > c[i]) atomicMax(&agg_enc[d[k][j]], v[i]);
        }
}

__global__ void gnn_edges_direct(const float* __restrict__ x,
                                 const int* __restrict__ ei,
                                 unsigned int* agg_enc) {
    const int4* src4 = reinterpret_cast<const int4*>(ei);
    const int4* dst4 = reinterpret_cast<const int4*>(ei + N_EDGES);
    const float2* x2 = reinterpret_cast<const float2*>(x);
    int tid = blockIdx.x * blockDim.x + threadIdx.x;
    int stride = gridDim.x * blockDim.x;
    const int n4 = N_EDGES / 4;
    for (int e4 = tid; e4 < n4; e4 += stride) {
        int4 s = src4[e4];
        int4 d = dst4[e4];
        float2 a = x2[s.x], b = x2[s.y], c = x2[s.z], e = x2[s.w];
        unsigned int va = enc_f32(a.x * a.y);
        unsigned int vb = enc_f32(b.x * b.y);
        unsigned int vc = enc_f32(c.x * c.y);
        unsigned int vd = enc_f32(e.x * e.y);
        unsigned int ca = agg_enc[d.x];
        unsigned int cb = agg_enc[d.y];
        unsigned int cc = agg_enc[d.z];
        unsigned int cd = agg_enc[d.w];
        if (va > ca) atomicMax(&agg_enc[d.x], va);
        if (vb > cb) atomicMax(&agg_enc[d.y], vb);
        if (vc > cc) atomicMax(&agg_enc[d.z], vc);
        if (vd > cd) atomicMax(&agg_enc[d.w], vd);
    }
}

__global__ void gnn_final(const float* __restrict__ x,
                          const float* __restrict__ w,
                          float* out) {
    int i = blockIdx.x * blockDim.x + threadIdx.x;
    if (i < N_NODES) {
        float2 v = reinterpret_cast<const float2*>(x)[i];
        float xp = v.x * v.y;
        unsigned int e = reinterpret_cast<const unsigned int*>(out)[i];
        float agg = dec_f32(e);
        out[i] = xp * w[0] + agg * w[1];
    }
}

extern "C" void kernel_launch(void* const* d_in, const int* in_sizes, int n_in,
                              void* d_out, int out_size, void* d_ws, size_t ws_size,
                              hipStream_t stream) {
    const float* x = (const float*)d_in[0];
    const int* ei = (const int*)d_in[1];     // int32 per harness contract (2 x N_EDGES)
    const float* w = (const float*)d_in[2];
    float* out = (float*)d_out;
    unsigned int* agg_enc = (unsigned int*)d_out;

    const int BLK = 256;
    const int nblk_nodes = (N_NODES + BLK - 1) / BLK;   // 1024

    if (ws_size >= WS_NEEDED) {
        char* ws = (char*)d_ws;
        unsigned int* cursors = (unsigned int*)(ws + WS_CURSOR_OFF);
        unsigned int* xp_ws = (unsigned int*)(ws + WS_XP_OFF);
        unsigned long long* bins = (unsigned long long*)(ws + WS_BINS_OFF);

        k_init<<<nblk_nodes, BLK, 0, stream>>>(x, agg_enc, xp_ws, cursors);
        k_part<<<NCHUNK, 256, 0, stream>>>(ei, xp_ws, bins, cursors, agg_enc);
        k_reduce<<<NBINS, 1024, 0, stream>>>(x, w, bins, cursors, out);
    } else if (ws_size >= (size_t)N_NODES * sizeof(unsigned int)) {
        unsigned int* xp_enc = (unsigned int*)d_ws;
        gnn_init2<<<nblk_nodes, BLK, 0, stream>>>(x, agg_enc, xp_enc);
        gnn_edges_ws<<<4096, BLK, 0, stream>>>(ei, xp_enc, agg_enc);
        gnn_final<<<nblk_nodes, BLK, 0, stream>>>(x, w, out);
    } else {
        gnn_init1<<<nblk_nodes, BLK, 0, stream>>>(x, agg_enc);
        gnn_edges_direct<<<2048, BLK, 0, stream>>>(x, ei, agg_enc);
        gnn_final<<<nblk_nodes, BLK, 0, stream>>>(x, w, out);
    }
}